// Round 15
// baseline (222.250 us; speedup 1.0000x reference)
//
#include <hip/hip_runtime.h>
#include <hip/hip_bf16.h>
#include <stdint.h>

#define T_TOK 2048
#define HD    1024
#define ID    4096
#define NE    8
#define NN2   8192   // 2*ID
#define CHUNK 256    // T_TOK / NE

typedef short          bf16x8 __attribute__((ext_vector_type(8)));
typedef float          f32x4  __attribute__((ext_vector_type(4)));
typedef unsigned short u16;
typedef u16            u16x4 __attribute__((ext_vector_type(4)));

__device__ __forceinline__ u16 f2bf(float f) {
    return __builtin_bit_cast(u16, __float2bfloat16(f));
}

// Barrier that does NOT drain vmcnt: LDS-ordering only (T3/T4 pattern).
__device__ __forceinline__ void lgkm_bar() {
    asm volatile("s_waitcnt lgkmcnt(0)" ::: "memory");
    __builtin_amdgcn_s_barrier();
}

// ---------------------------------------------------------------- router ----
// Per-token routing + x->bf16, PLUS fused one-shot bf16 conversion of the
// multiply-reused weights (sgw/suw/sdw): the GEMMs round B to bf16 anyway
// (f2bf before LDS), so converting once halves their pipe bytes at zero
// accuracy cost. gup/dwn stay fp32 (read-once; conversion wouldn't pay).
__global__ __launch_bounds__(256) void k_router(
    const float* __restrict__ x, const float* __restrict__ rw,
    const float* __restrict__ sgw, const float* __restrict__ suw,
    const float* __restrict__ sdw,
    float* __restrict__ scoresT, u16* __restrict__ xbf, u16* __restrict__ xsbf,
    u16* __restrict__ sgwc, u16* __restrict__ suwc, u16* __restrict__ sdwc)
{
    const int t   = blockIdx.x;
    const int tid = threadIdx.x;
    __shared__ float wred[NE][4];
    __shared__ float ssc;

    float4 xv = reinterpret_cast<const float4*>(x + (size_t)t * HD)[tid];
    float p[NE];
#pragma unroll
    for (int e = 0; e < NE; ++e) p[e] = 0.f;
    const float* wrow = rw + (size_t)tid * 4 * NE;
    float xj[4] = {xv.x, xv.y, xv.z, xv.w};
#pragma unroll
    for (int j = 0; j < 4; ++j)
#pragma unroll
        for (int e = 0; e < NE; ++e) p[e] += xj[j] * wrow[j * NE + e];

#pragma unroll
    for (int e = 0; e < NE; ++e) {
        float v = p[e];
#pragma unroll
        for (int o = 32; o > 0; o >>= 1) v += __shfl_down(v, o, 64);
        if ((tid & 63) == 0) wred[e][tid >> 6] = v;
    }
    __syncthreads();
    if (tid == 0) {
        float mx = -3.4e38f; int am = 0;
        float lg[NE];
#pragma unroll
        for (int e = 0; e < NE; ++e) {
            lg[e] = wred[e][0] + wred[e][1] + wred[e][2] + wred[e][3];
            if (lg[e] > mx) { mx = lg[e]; am = e; }
        }
        float sc = 1.f / (1.f + __expf(-mx));
        ssc = sc;
#pragma unroll
        for (int e = 0; e < NE; ++e)
            scoresT[(size_t)e * T_TOK + t] = (e == am) ? sc : 0.f;
    }
    __syncthreads();
    const float sc = ssc;
    ushort4 a, b;
    a.x = f2bf(xj[0]); a.y = f2bf(xj[1]); a.z = f2bf(xj[2]); a.w = f2bf(xj[3]);
    b.x = f2bf(xj[0] * sc); b.y = f2bf(xj[1] * sc); b.z = f2bf(xj[2] * sc); b.w = f2bf(xj[3] * sc);
    reinterpret_cast<ushort4*>(xbf  + (size_t)t * HD)[tid] = a;
    reinterpret_cast<ushort4*>(xsbf + (size_t)t * HD)[tid] = b;

    // fused weight conversion: 3 matrices x 4M floats = 1M f32x4 each;
    // 524288 threads x 2 strided f32x4 per matrix.
    {
        const size_t gt  = (size_t)blockIdx.x * 256 + tid;
        const size_t NTH = (size_t)T_TOK * 256;          // 524288
#pragma unroll
        for (int r = 0; r < 2; ++r) {
            const size_t i = gt + (size_t)r * NTH;       // < 1048576
            f32x4 v; u16x4 h;
            v = __builtin_nontemporal_load(reinterpret_cast<const f32x4*>(sgw) + i);
            h[0] = f2bf(v[0]); h[1] = f2bf(v[1]); h[2] = f2bf(v[2]); h[3] = f2bf(v[3]);
            reinterpret_cast<u16x4*>(sgwc)[i] = h;
            v = __builtin_nontemporal_load(reinterpret_cast<const f32x4*>(suw) + i);
            h[0] = f2bf(v[0]); h[1] = f2bf(v[1]); h[2] = f2bf(v[2]); h[3] = f2bf(v[3]);
            reinterpret_cast<u16x4*>(suwc)[i] = h;
            v = __builtin_nontemporal_load(reinterpret_cast<const f32x4*>(sdw) + i);
            h[0] = f2bf(v[0]); h[1] = f2bf(v[1]); h[2] = f2bf(v[2]); h[3] = f2bf(v[3]);
            reinterpret_cast<u16x4*>(sdwc)[i] = h;
        }
    }
}

// ------------------------------------------------------------------- G1 -----
// r13 split kept; delta: shared half (EXPERT=0) loads B from the bf16 copies
// (half the pipe bytes). Expert half unchanged (gup fp32 + nt).
// BM=256, BN=128, BK=32, 8 waves (4x2), dual-bank A direct from global,
// depth-2 B reg-staged into dbuf LDS, lgkm-only barriers.
template<bool EXPERT>
__global__ __launch_bounds__(512, 2) void k_gemm1(
    const u16* __restrict__ xbf, const u16* __restrict__ xsbf,
    const u16* __restrict__ sgwc, const u16* __restrict__ suwc,
    const float* __restrict__ gup, u16* __restrict__ h2)
{
    constexpr int BM = 256, BN = 128, BK = 32, NS = HD / BK;   // 32 steps
    const int d = blockIdx.x;                                  // 256 blocks/half
    int mt, nt;
    if constexpr (!EXPERT) { const int r = d & 7, q = d >> 3; nt = r + 8 * (q & 3); mt = q >> 2; }
    else                   { mt = d & 7; nt = 32 + (d >> 3); }
    const int m0 = mt * BM, n0 = nt * BN;

    const u16* A = EXPERT ? xsbf : xbf;

    __shared__ u16 Bgs[2][BN * BK];
    __shared__ u16 Bus[2][BN * BK];

    const int tid  = threadIdx.x;
    const int lane = tid & 63, wid = tid >> 6;
    const int wr = wid >> 1, wc = wid & 1;        // 4 x 2 wave grid
    const int lrow = lane & 15, kg = lane >> 4;

    f32x4 accg[4][4], accu[4][4];
#pragma unroll
    for (int i = 0; i < 4; ++i)
#pragma unroll
        for (int j = 0; j < 4; ++j)
#pragma unroll
            for (int r = 0; r < 4; ++r) { accg[i][j][r] = 0.f; accu[i][j][r] = 0.f; }

    const int bcol = tid & 127, bkh = tid >> 7;   // B: 128 cols x 4 k-octets
    const int bsw  = (bcol >> 1) & 3;
    const u16* aBase = A + (size_t)(m0 + wr * 64 + lrow) * HD + kg * 8;

    bf16x8 aF0[4], aF1[4];

#define LOADA(ks, F) do {                                                       \
        _Pragma("unroll")                                                       \
        for (int mf = 0; mf < 4; ++mf)                                          \
            F[mf] = *reinterpret_cast<const bf16x8*>(                           \
                aBase + (size_t)mf * 16 * HD + (ks) * BK);                      \
    } while (0)

#define MFMAPH(b, F) do {                                                       \
        const char* gs_ = (const char*)Bgs[b];                                  \
        const char* us_ = (const char*)Bus[b];                                  \
        bf16x8 bgf_[4], buf_[4];                                                \
        _Pragma("unroll")                                                       \
        for (int nf = 0; nf < 4; ++nf) {                                        \
            const int col_ = wc * 64 + nf * 16 + lrow;                          \
            const int so_  = col_ * 64 + ((kg ^ ((col_ >> 1) & 3)) * 16);       \
            bgf_[nf] = *reinterpret_cast<const bf16x8*>(gs_ + so_);             \
            buf_[nf] = *reinterpret_cast<const bf16x8*>(us_ + so_);             \
        }                                                                       \
        _Pragma("unroll")                                                       \
        for (int mf = 0; mf < 4; ++mf)                                          \
            _Pragma("unroll")                                                   \
            for (int nf = 0; nf < 4; ++nf) {                                    \
                accg[mf][nf] = __builtin_amdgcn_mfma_f32_16x16x32_bf16(         \
                    F[mf], bgf_[nf], accg[mf][nf], 0, 0, 0);                    \
                accu[mf][nf] = __builtin_amdgcn_mfma_f32_16x16x32_bf16(         \
                    F[mf], buf_[nf], accu[mf][nf], 0, 0, 0);                    \
            }                                                                   \
    } while (0)

#define LDSW(b, wg_, wu_)                                                       \
        *reinterpret_cast<bf16x8*>(reinterpret_cast<char*>(Bgs[b])              \
            + bcol * 64 + ((bkh ^ bsw) * 16)) = wg_;                            \
        *reinterpret_cast<bf16x8*>(reinterpret_cast<char*>(Bus[b])              \
            + bcol * 64 + ((bkh ^ bsw) * 16)) = wu_

    if constexpr (!EXPERT) {
        // -------- shared half: bf16 B loads (half pipe bytes) --------
        const u16* Bg = sgwc + n0;
        const u16* Bu = suwc + n0;
        u16 g0[8], u0[8], g1[8], u1[8];

#define LOADBH(ks, rg, ru) do {                                                 \
        const u16* bgp_ = Bg + (size_t)((ks) * BK + bkh * 8) * ID + bcol;       \
        const u16* bup_ = Bu + (size_t)((ks) * BK + bkh * 8) * ID + bcol;       \
        _Pragma("unroll")                                                       \
        for (int j = 0; j < 8; ++j) { rg[j] = bgp_[(size_t)j * ID];             \
                                      ru[j] = bup_[(size_t)j * ID]; }           \
    } while (0)

#define STOREBH(b, rg, ru) do {                                                 \
        bf16x8 wg_, wu_;                                                        \
        _Pragma("unroll")                                                       \
        for (int j = 0; j < 8; ++j) { wg_[j] = (short)rg[j];                    \
                                      wu_[j] = (short)ru[j]; }                  \
        LDSW(b, wg_, wu_);                                                      \
    } while (0)

        LOADBH(0, g0, u0);
        LOADBH(1, g1, u1);
        LOADA(0, aF0);
        STOREBH(0, g0, u0);
        lgkm_bar();
        for (int j = 0; j < NS / 2; ++j) {
            const int ks = 2 * j;
            {
                const int ka = (ks + 1 < NS) ? ks + 1 : NS - 1;
                const int kb = (ks + 2 < NS) ? ks + 2 : NS - 1;
                LOADA(ka, aF1);
                LOADBH(kb, g0, u0);
            }
            MFMAPH(0, aF0);
            STOREBH(1, g1, u1);
            lgkm_bar();
            {
                const int ka = (ks + 2 < NS) ? ks + 2 : NS - 1;
                const int kb = (ks + 3 < NS) ? ks + 3 : NS - 1;
                LOADA(ka, aF0);
                LOADBH(kb, g1, u1);
            }
            MFMAPH(1, aF1);
            STOREBH(0, g0, u0);
            lgkm_bar();
        }
#undef LOADBH
#undef STOREBH
    } else {
        // -------- expert half: fp32 gup + nt (read-once) --------
        const float* Bg = gup + (size_t)mt * HD * NN2 + (n0 - ID);
        const float* Bu = Bg + ID;
        float g0[8], u0[8], g1[8], u1[8];

#define LOADBF(ks, rg, ru) do {                                                 \
        const float* bgp_ = Bg + (size_t)((ks) * BK + bkh * 8) * NN2 + bcol;    \
        const float* bup_ = Bu + (size_t)((ks) * BK + bkh * 8) * NN2 + bcol;    \
        _Pragma("unroll")                                                       \
        for (int j = 0; j < 8; ++j) {                                           \
            rg[j] = __builtin_nontemporal_load(bgp_ + (size_t)j * NN2);         \
            ru[j] = __builtin_nontemporal_load(bup_ + (size_t)j * NN2);         \
        }                                                                       \
    } while (0)

#define STOREBF(b, rg, ru) do {                                                 \
        bf16x8 wg_, wu_;                                                        \
        _Pragma("unroll")                                                       \
        for (int j = 0; j < 8; ++j) { wg_[j] = (short)f2bf(rg[j]);              \
                                      wu_[j] = (short)f2bf(ru[j]); }            \
        LDSW(b, wg_, wu_);                                                      \
    } while (0)

        LOADBF(0, g0, u0);
        LOADBF(1, g1, u1);
        LOADA(0, aF0);
        STOREBF(0, g0, u0);
        lgkm_bar();
        for (int j = 0; j < NS / 2; ++j) {
            const int ks = 2 * j;
            {
                const int ka = (ks + 1 < NS) ? ks + 1 : NS - 1;
                const int kb = (ks + 2 < NS) ? ks + 2 : NS - 1;
                LOADA(ka, aF1);
                LOADBF(kb, g0, u0);
            }
            MFMAPH(0, aF0);
            STOREBF(1, g1, u1);
            lgkm_bar();
            {
                const int ka = (ks + 2 < NS) ? ks + 2 : NS - 1;
                const int kb = (ks + 3 < NS) ? ks + 3 : NS - 1;
                LOADA(ka, aF0);
                LOADBF(kb, g1, u1);
            }
            MFMAPH(1, aF1);
            STOREBF(0, g0, u0);
            lgkm_bar();
        }
#undef LOADBF
#undef STOREBF
    }
#undef LOADA
#undef MFMAPH
#undef LDSW

    // SwiGLU epilogue -> bf16 H2
#pragma unroll
    for (int mf = 0; mf < 4; ++mf)
#pragma unroll
        for (int nf = 0; nf < 4; ++nf) {
            const int col = n0 + wc * 64 + nf * 16 + lrow;
#pragma unroll
            for (int r = 0; r < 4; ++r) {
                const int row = m0 + wr * 64 + mf * 16 + kg * 4 + r;
                const float g = accg[mf][nf][r];
                const float u = accu[mf][nf][r];
                const float h = (g / (1.f + __expf(-g))) * u;
                h2[(size_t)row * NN2 + col] = f2bf(h);
            }
        }
}

// ------------------------------------------------------------------- G2 -----
// r11 configuration; delta: kh=0 (sdw) half loads the bf16 copy (half pipe
// bytes); kh=1 (dwn, read-once) stays fp32. Block-uniform branch.
__global__ __launch_bounds__(512, 1) void k_gemm2(
    const u16* __restrict__ h2, const u16* __restrict__ sdwc,
    const float* __restrict__ dwn, float* __restrict__ out)
{
    constexpr int BM = 256, BN = 64, BK = 64, NS = 2048 / BK;  // 32 steps/waveset
    const int d   = blockIdx.x;               // 256 blocks
    const int mt  = d & 7;                    // = XCD
    const int q   = d >> 3;
    const int kh  = q & 1;                    // K-half: 0=sdw(bf16), 1=dwn(fp32)
    const int nt  = q >> 1;                   // 0..15
    const int m0 = mt * BM, n0 = nt * BN;

    const int tid = threadIdx.x;
    const int ws  = tid >> 8;                 // waveset 0/1
    const int wt  = tid & 255;
    const int lane = wt & 63, wid4 = wt >> 6;
    const int wr = wid4;                      // 4x1 wave grid
    const int lrow = lane & 15, kg = lane >> 4;

    __shared__ char smem[65536];
    u16*   BsBase = (u16*)smem;
    float* red    = (float*)smem;

    f32x4 acc[4][4];
#pragma unroll
    for (int i = 0; i < 4; ++i)
#pragma unroll
        for (int j = 0; j < 4; ++j)
#pragma unroll
            for (int r = 0; r < 4; ++r) acc[i][j][r] = 0.f;

    const u16* aBase = h2 + (size_t)(m0 + wr * 64 + lrow) * NN2
                          + (size_t)kh * ID + (size_t)ws * 2048 + kg * 8;

    const int bcol = wt & 63, bkq = wt >> 6;
    const int bsw  = bcol & 7;

    bf16x8 aF0[8], aF1[8];

#define LOADA2(ks, F) do {                                                      \
        _Pragma("unroll")                                                       \
        for (int mf = 0; mf < 4; ++mf)                                          \
            _Pragma("unroll")                                                   \
            for (int kk = 0; kk < 2; ++kk)                                      \
                F[mf * 2 + kk] = *reinterpret_cast<const bf16x8*>(              \
                    aBase + (size_t)mf * 16 * NN2 + (ks) * BK + kk * 32);       \
    } while (0)

#define LDSW2(b, w0_, w1_) do {                                                 \
        char* bs_ = (char*)(BsBase + (size_t)(ws * 2 + (b)) * BN * BK);         \
        *reinterpret_cast<bf16x8*>(bs_ + bcol * 128 + (((bkq * 2 + 0) ^ bsw) * 16)) = w0_; \
        *reinterpret_cast<bf16x8*>(bs_ + bcol * 128 + (((bkq * 2 + 1) ^ bsw) * 16)) = w1_; \
    } while (0)

#define MFMAPH2(b, F) do {                                                      \
        const char* bs_ = (const char*)(BsBase + (size_t)(ws * 2 + (b)) * BN * BK); \
        _Pragma("unroll")                                                       \
        for (int kk = 0; kk < 2; ++kk) {                                        \
            bf16x8 bf_[4];                                                      \
            _Pragma("unroll")                                                   \
            for (int nf = 0; nf < 4; ++nf) {                                    \
                const int col_ = nf * 16 + lrow;                                \
                bf_[nf] = *reinterpret_cast<const bf16x8*>(                     \
                    bs_ + col_ * 128 + (((kk * 4 + kg) ^ (col_ & 7)) * 16));    \
            }                                                                   \
            _Pragma("unroll")                                                   \
            for (int mf = 0; mf < 4; ++mf)                                      \
                _Pragma("unroll")                                               \
                for (int nf = 0; nf < 4; ++nf)                                  \
                    acc[mf][nf] = __builtin_amdgcn_mfma_f32_16x16x32_bf16(      \
                        F[mf * 2 + kk], bf_[nf], acc[mf][nf], 0, 0, 0);         \
        }                                                                       \
    } while (0)

    if (kh == 0) {
        // -------- sdw half: bf16 B --------
        const u16* Bbase = sdwc + (size_t)(ws * 2048) * HD;
        u16 rb0[16], rb1[16];

#define LOADB2H(ks, rb) do {                                                    \
        const u16* bb_ = Bbase + (size_t)((ks) * BK + bkq * 16) * HD + n0 + bcol; \
        _Pragma("unroll")                                                       \
        for (int j = 0; j < 16; ++j) rb[j] = bb_[(size_t)j * HD];               \
    } while (0)

#define STOREB2H(b, rb) do {                                                    \
        bf16x8 w0_, w1_;                                                        \
        _Pragma("unroll")                                                       \
        for (int j = 0; j < 8; ++j) { w0_[j] = (short)rb[j];                    \
                                      w1_[j] = (short)rb[8 + j]; }              \
        LDSW2(b, w0_, w1_);                                                     \
    } while (0)

        LOADB2H(0, rb0);
        LOADB2H(1, rb1);
        LOADA2(0, aF0);
        STOREB2H(0, rb0);
        lgkm_bar();
        for (int j = 0; j < NS / 2; ++j) {
            const int ks = 2 * j;
            {
                const int ka = (ks + 1 < NS) ? ks + 1 : NS - 1;
                const int kb = (ks + 2 < NS) ? ks + 2 : NS - 1;
                LOADA2(ka, aF1);
                LOADB2H(kb, rb0);
            }
            MFMAPH2(0, aF0);
            STOREB2H(1, rb1);
            lgkm_bar();
            {
                const int ka = (ks + 2 < NS) ? ks + 2 : NS - 1;
                const int kb = (ks + 3 < NS) ? ks + 3 : NS - 1;
                LOADA2(ka, aF0);
                LOADB2H(kb, rb1);
            }
            MFMAPH2(1, aF1);
            STOREB2H(0, rb0);
            lgkm_bar();
        }
#undef LOADB2H
#undef STOREB2H
    } else {
        // -------- dwn half: fp32 B (read-once) --------
        const float* Bbase = dwn + (size_t)mt * ID * HD + (size_t)(ws * 2048) * HD;
        float rb0[16], rb1[16];

#define LOADB2F(ks, rb) do {                                                    \
        const float* bb_ = Bbase + (size_t)((ks) * BK + bkq * 16) * HD + n0 + bcol; \
        _Pragma("unroll")                                                       \
        for (int j = 0; j < 16; ++j) rb[j] = bb_[(size_t)j * HD];               \
    } while (0)

#define STOREB2F(b, rb) do {                                                    \
        bf16x8 w0_, w1_;                                                        \
        _Pragma("unroll")                                                       \
        for (int j = 0; j < 8; ++j) { w0_[j] = (short)f2bf(rb[j]);              \
                                      w1_[j] = (short)f2bf(rb[8 + j]); }        \
        LDSW2(b, w0_, w1_);                                                     \
    } while (0)

        LOADB2F(0, rb0);
        LOADB2F(1, rb1);
        LOADA2(0, aF0);
        STOREB2F(0, rb0);
        lgkm_bar();
        for (int j = 0; j < NS / 2; ++j) {
            const int ks = 2 * j;
            {
                const int ka = (ks + 1 < NS) ? ks + 1 : NS - 1;
                const int kb = (ks + 2 < NS) ? ks + 2 : NS - 1;
                LOADA2(ka, aF1);
                LOADB2F(kb, rb0);
            }
            MFMAPH2(0, aF0);
            STOREB2F(1, rb1);
            lgkm_bar();
            {
                const int ka = (ks + 2 < NS) ? ks + 2 : NS - 1;
                const int kb = (ks + 3 < NS) ? ks + 3 : NS - 1;
                LOADA2(ka, aF0);
                LOADB2F(kb, rb1);
            }
            MFMAPH2(1, aF1);
            STOREB2F(0, rb0);
            lgkm_bar();
        }
#undef LOADB2F
#undef STOREB2F
    }
#undef LOADA2
#undef LDSW2
#undef MFMAPH2

    // waveset reduce + atomic kh-combine
    lgkm_bar();
    if (ws == 1) {
#pragma unroll
        for (int mf = 0; mf < 4; ++mf)
#pragma unroll
            for (int nf = 0; nf < 4; ++nf)
#pragma unroll
                for (int r = 0; r < 4; ++r) {
                    const int row = wr * 64 + mf * 16 + kg * 4 + r;
                    const int col = nf * 16 + lrow;
                    red[row * 64 + col] = acc[mf][nf][r];
                }
    }
    lgkm_bar();
    if (ws == 0) {
#pragma unroll
        for (int mf = 0; mf < 4; ++mf)
#pragma unroll
            for (int nf = 0; nf < 4; ++nf)
#pragma unroll
                for (int r = 0; r < 4; ++r) {
                    const int row = wr * 64 + mf * 16 + kg * 4 + r;
                    const int col = nf * 16 + lrow;
                    atomicAdd(&out[(size_t)(m0 + row) * HD + n0 + col],
                              acc[mf][nf][r] + red[row * 64 + col]);
                }
    }
}

// --------------------------------------------------------------- launch -----
extern "C" void kernel_launch(void* const* d_in, const int* in_sizes, int n_in,
                              void* d_out, int out_size, void* d_ws, size_t ws_size,
                              hipStream_t stream) {
    const float* x   = (const float*)d_in[0];
    const float* rw  = (const float*)d_in[1];
    const float* gup = (const float*)d_in[2];
    const float* dwn = (const float*)d_in[3];
    const float* sgw = (const float*)d_in[4];
    const float* suw = (const float*)d_in[5];
    const float* sdw = (const float*)d_in[6];

    float* out     = (float*)d_out;
    float* scoresT = out + (size_t)T_TOK * HD;

    char* ws   = (char*)d_ws;
    u16* xbf   = (u16*)ws;                                    //  0..4  MB
    u16* xsbf  = (u16*)(ws + (size_t)T_TOK * HD * 2);         //  4..8  MB
    u16* h2    = (u16*)(ws + (size_t)2 * T_TOK * HD * 2);     //  8..40 MB
    u16* sgwc  = (u16*)(ws + (size_t)40 * 1024 * 1024);       // 40..48 MB
    u16* suwc  = (u16*)(ws + (size_t)48 * 1024 * 1024);       // 48..56 MB
    u16* sdwc  = (u16*)(ws + (size_t)56 * 1024 * 1024);       // 56..64 MB

    // zero the final-output region: G2 accumulates kh-partials atomically
    (void)hipMemsetAsync(out, 0, (size_t)T_TOK * HD * sizeof(float), stream);

    k_router<<<T_TOK, 256, 0, stream>>>(x, rw, sgw, suw, sdw,
                                        scoresT, xbf, xsbf, sgwc, suwc, sdwc);
    k_gemm1<false><<<256, 512, 0, stream>>>(xbf, xsbf, sgwc, suwc, gup, h2);
    k_gemm1<true ><<<256, 512, 0, stream>>>(xbf, xsbf, sgwc, suwc, gup, h2);
    k_gemm2<<<256, 512, 0, stream>>>(h2, sdwc, dwn, out);
}

// Round 16
// 211.901 us; speedup vs baseline: 1.0488x; 1.0488x over previous
//
#include <hip/hip_runtime.h>
#include <hip/hip_bf16.h>
#include <stdint.h>

#define T_TOK 2048
#define HD    1024
#define ID    4096
#define NE    8
#define NN2   8192   // 2*ID
#define CHUNK 256    // T_TOK / NE

typedef short          bf16x8 __attribute__((ext_vector_type(8)));
typedef float          f32x4  __attribute__((ext_vector_type(4)));
typedef unsigned short u16;

__device__ __forceinline__ u16 f2bf(float f) {
    return __builtin_bit_cast(u16, __float2bfloat16(f));
}

// Barrier that does NOT drain vmcnt: LDS-ordering only (T3/T4 pattern).
__device__ __forceinline__ void lgkm_bar() {
    asm volatile("s_waitcnt lgkmcnt(0)" ::: "memory");
    __builtin_amdgcn_s_barrier();
}

// ---------------------------------------------------------------- router ----
__global__ __launch_bounds__(256) void k_router(
    const float* __restrict__ x, const float* __restrict__ rw,
    float* __restrict__ scoresT, u16* __restrict__ xbf, u16* __restrict__ xsbf)
{
    const int t   = blockIdx.x;
    const int tid = threadIdx.x;
    __shared__ float wred[NE][4];
    __shared__ float ssc;

    float4 xv = reinterpret_cast<const float4*>(x + (size_t)t * HD)[tid];
    float p[NE];
#pragma unroll
    for (int e = 0; e < NE; ++e) p[e] = 0.f;
    const float* wrow = rw + (size_t)tid * 4 * NE;
    float xj[4] = {xv.x, xv.y, xv.z, xv.w};
#pragma unroll
    for (int j = 0; j < 4; ++j)
#pragma unroll
        for (int e = 0; e < NE; ++e) p[e] += xj[j] * wrow[j * NE + e];

#pragma unroll
    for (int e = 0; e < NE; ++e) {
        float v = p[e];
#pragma unroll
        for (int o = 32; o > 0; o >>= 1) v += __shfl_down(v, o, 64);
        if ((tid & 63) == 0) wred[e][tid >> 6] = v;
    }
    __syncthreads();
    if (tid == 0) {
        float mx = -3.4e38f; int am = 0;
        float lg[NE];
#pragma unroll
        for (int e = 0; e < NE; ++e) {
            lg[e] = wred[e][0] + wred[e][1] + wred[e][2] + wred[e][3];
            if (lg[e] > mx) { mx = lg[e]; am = e; }
        }
        float sc = 1.f / (1.f + __expf(-mx));
        ssc = sc;
#pragma unroll
        for (int e = 0; e < NE; ++e)
            scoresT[(size_t)e * T_TOK + t] = (e == am) ? sc : 0.f;
    }
    __syncthreads();
    const float sc = ssc;
    ushort4 a, b;
    a.x = f2bf(xj[0]); a.y = f2bf(xj[1]); a.z = f2bf(xj[2]); a.w = f2bf(xj[3]);
    b.x = f2bf(xj[0] * sc); b.y = f2bf(xj[1] * sc); b.z = f2bf(xj[2] * sc); b.w = f2bf(xj[3] * sc);
    reinterpret_cast<ushort4*>(xbf  + (size_t)t * HD)[tid] = a;
    reinterpret_cast<ushort4*>(xsbf + (size_t)t * HD)[tid] = b;
}

// ------------------------------------------------------------------- G1 -----
// Session-best configuration (r10/r11, ~110 us): BM=256, BN=128, BK=32,
// 8 waves (4x2), wave 64x64. A direct from global (dual-bank depth-1
// prefetch), B fp32 reg-staged depth-2 into dbuf LDS, NON-TEMPORAL B loads
// (stream-once weights stay out of L1/L2; A slab stays hot), lgkm-only
// barriers so prefetches ride across steps.
__global__ __launch_bounds__(512, 2) void k_gemm1(
    const u16* __restrict__ xbf, const u16* __restrict__ xsbf,
    const float* __restrict__ sgw, const float* __restrict__ suw,
    const float* __restrict__ gup, u16* __restrict__ h2)
{
    constexpr int BM = 256, BN = 128, BK = 32, NS = HD / BK;   // 32 steps
    const int d = blockIdx.x;
    int mt, nt;
    if (d < 256) { const int r = d & 7, q = d >> 3; nt = r + 8 * (q & 3); mt = q >> 2; }
    else         { const int e = d - 256;           mt = e & 7; nt = 32 + (e >> 3); }
    const int m0 = mt * BM, n0 = nt * BN;

    const u16* A; const float* Bg; const float* Bu; int ldb;
    if (n0 < ID) { A = xbf; Bg = sgw + n0; Bu = suw + n0; ldb = ID; }
    else {
        A = xsbf;
        Bg = gup + (size_t)mt * HD * NN2 + (n0 - ID);
        Bu = Bg + ID;
        ldb = NN2;
    }

    __shared__ u16 Bgs[2][BN * BK];
    __shared__ u16 Bus[2][BN * BK];

    const int tid  = threadIdx.x;
    const int lane = tid & 63, wid = tid >> 6;
    const int wr = wid >> 1, wc = wid & 1;        // 4 x 2 wave grid
    const int lrow = lane & 15, kg = lane >> 4;

    f32x4 accg[4][4], accu[4][4];
#pragma unroll
    for (int i = 0; i < 4; ++i)
#pragma unroll
        for (int j = 0; j < 4; ++j)
#pragma unroll
            for (int r = 0; r < 4; ++r) { accg[i][j][r] = 0.f; accu[i][j][r] = 0.f; }

    const int bcol = tid & 127, bkh = tid >> 7;   // B: 128 cols x 4 k-octets
    const int bsw  = (bcol >> 1) & 3;
    const u16* aBase = A + (size_t)(m0 + wr * 64 + lrow) * HD + kg * 8;

    float g0[8], u0[8], g1[8], u1[8];
    bf16x8 aF0[4], aF1[4];

#define LOADB(ks, rg, ru) do {                                                  \
        const float* bgp_ = Bg + (size_t)((ks) * BK + bkh * 8) * ldb + bcol;    \
        const float* bup_ = Bu + (size_t)((ks) * BK + bkh * 8) * ldb + bcol;    \
        _Pragma("unroll")                                                       \
        for (int j = 0; j < 8; ++j) {                                           \
            rg[j] = __builtin_nontemporal_load(bgp_ + (size_t)j * ldb);         \
            ru[j] = __builtin_nontemporal_load(bup_ + (size_t)j * ldb);         \
        }                                                                       \
    } while (0)

#define STOREB(b, rg, ru) do {                                                  \
        bf16x8 wg_, wu_;                                                        \
        _Pragma("unroll")                                                       \
        for (int j = 0; j < 8; ++j) { wg_[j] = (short)f2bf(rg[j]);              \
                                      wu_[j] = (short)f2bf(ru[j]); }            \
        *reinterpret_cast<bf16x8*>(reinterpret_cast<char*>(Bgs[b])              \
            + bcol * 64 + ((bkh ^ bsw) * 16)) = wg_;                            \
        *reinterpret_cast<bf16x8*>(reinterpret_cast<char*>(Bus[b])              \
            + bcol * 64 + ((bkh ^ bsw) * 16)) = wu_;                            \
    } while (0)

#define LOADA(ks, F) do {                                                       \
        _Pragma("unroll")                                                       \
        for (int mf = 0; mf < 4; ++mf)                                          \
            F[mf] = *reinterpret_cast<const bf16x8*>(                           \
                aBase + (size_t)mf * 16 * HD + (ks) * BK);                      \
    } while (0)

#define MFMAPH(b, F) do {                                                       \
        const char* gs_ = (const char*)Bgs[b];                                  \
        const char* us_ = (const char*)Bus[b];                                  \
        bf16x8 bgf_[4], buf_[4];                                                \
        _Pragma("unroll")                                                       \
        for (int nf = 0; nf < 4; ++nf) {                                        \
            const int col_ = wc * 64 + nf * 16 + lrow;                          \
            const int so_  = col_ * 64 + ((kg ^ ((col_ >> 1) & 3)) * 16);       \
            bgf_[nf] = *reinterpret_cast<const bf16x8*>(gs_ + so_);             \
            buf_[nf] = *reinterpret_cast<const bf16x8*>(us_ + so_);             \
        }                                                                       \
        _Pragma("unroll")                                                       \
        for (int mf = 0; mf < 4; ++mf)                                          \
            _Pragma("unroll")                                                   \
            for (int nf = 0; nf < 4; ++nf) {                                    \
                accg[mf][nf] = __builtin_amdgcn_mfma_f32_16x16x32_bf16(         \
                    F[mf], bgf_[nf], accg[mf][nf], 0, 0, 0);                    \
                accu[mf][nf] = __builtin_amdgcn_mfma_f32_16x16x32_bf16(         \
                    F[mf], buf_[nf], accu[mf][nf], 0, 0, 0);                    \
            }                                                                   \
    } while (0)

    // prologue
    LOADB(0, g0, u0);
    LOADB(1, g1, u1);
    LOADA(0, aF0);
    STOREB(0, g0, u0);
    lgkm_bar();

    for (int j = 0; j < NS / 2; ++j) {
        const int ks = 2 * j;
        {
            const int ka = (ks + 1 < NS) ? ks + 1 : NS - 1;
            const int kb = (ks + 2 < NS) ? ks + 2 : NS - 1;
            LOADA(ka, aF1);
            LOADB(kb, g0, u0);
        }
        MFMAPH(0, aF0);
        STOREB(1, g1, u1);
        lgkm_bar();
        {
            const int ka = (ks + 2 < NS) ? ks + 2 : NS - 1;
            const int kb = (ks + 3 < NS) ? ks + 3 : NS - 1;
            LOADA(ka, aF0);
            LOADB(kb, g1, u1);
        }
        MFMAPH(1, aF1);
        STOREB(0, g0, u0);
        lgkm_bar();
    }
#undef LOADB
#undef STOREB
#undef LOADA
#undef MFMAPH

    // SwiGLU epilogue -> bf16 H2
#pragma unroll
    for (int mf = 0; mf < 4; ++mf)
#pragma unroll
        for (int nf = 0; nf < 4; ++nf) {
            const int col = n0 + wc * 64 + nf * 16 + lrow;
#pragma unroll
            for (int r = 0; r < 4; ++r) {
                const int row = m0 + wr * 64 + mf * 16 + kg * 4 + r;
                const float g = accg[mf][nf][r];
                const float u = accu[mf][nf][r];
                const float h = (g / (1.f + __expf(-g))) * u;
                h2[(size_t)row * NN2 + col] = f2bf(h);
            }
        }
}

// ------------------------------------------------------------------- G2 -----
// Session-best configuration (r11, ~92 us): BM=256 (=CHUNK), BN=64,
// K SPLIT ACROSS BLOCKS: kh=0 -> shared_down K=[0,4096); kh=1 -> dwn[mt].
// Grid 256 = 8 mt x 16 nt x 2 kh; mt pinned to XCD (h2 slab L2-hot, 16x
// reuse). 2 wavesets x 4 waves over K-quarters (BK=64, NS=32), depth-2 B,
// dual-bank A, lgkm barriers; LDS waveset-reduce; kh-partials combined by
// atomicAdd onto zeroed out (2 commutative addends/address).
__global__ __launch_bounds__(512, 1) void k_gemm2(
    const u16* __restrict__ h2, const float* __restrict__ sdw,
    const float* __restrict__ dwn, float* __restrict__ out)
{
    constexpr int BM = 256, BN = 64, BK = 64, NS = 2048 / BK;  // 32 steps/waveset
    const int d   = blockIdx.x;               // 256 blocks
    const int mt  = d & 7;                    // = XCD
    const int q   = d >> 3;
    const int kh  = q & 1;                    // K-half: 0=sdw, 1=dwn[mt]
    const int nt  = q >> 1;                   // 0..15
    const int m0 = mt * BM, n0 = nt * BN;

    const int tid = threadIdx.x;
    const int ws  = tid >> 8;                 // waveset 0/1
    const int wt  = tid & 255;
    const int lane = wt & 63, wid4 = wt >> 6; // 4 waves per waveset
    const int wr = wid4;                      // 4x1 wave grid, 64 rows each
    const int lrow = lane & 15, kg = lane >> 4;

    __shared__ char smem[65536];              // 32 KB staging, reused as reduce
    u16*   BsBase = (u16*)smem;               // [set][buf][BN*BK]
    float* red    = (float*)smem;             // 256 x 64 f32

    f32x4 acc[4][4];
#pragma unroll
    for (int i = 0; i < 4; ++i)
#pragma unroll
        for (int j = 0; j < 4; ++j)
#pragma unroll
            for (int r = 0; r < 4; ++r) acc[i][j][r] = 0.f;

    const float* Bbase = kh ? (dwn + (size_t)mt * ID * HD + (size_t)(ws * 2048) * HD)
                            : (sdw + (size_t)(ws * 2048) * HD);
    const u16* aBase = h2 + (size_t)(m0 + wr * 64 + lrow) * NN2
                          + (size_t)kh * ID + (size_t)ws * 2048 + kg * 8;

    const int bcol = wt & 63, bkq = wt >> 6;  // 64 cols x 4 k-16-groups
    const int bsw  = bcol & 7;

    float rb0[16], rb1[16];
    bf16x8 aF0[8], aF1[8];

#define LOADB2(ks, rb) do {                                                     \
        const float* bb_ = Bbase + (size_t)((ks) * BK + bkq * 16) * HD + n0 + bcol; \
        _Pragma("unroll")                                                       \
        for (int j = 0; j < 16; ++j) rb[j] = bb_[(size_t)j * HD];               \
    } while (0)

#define STOREB2(b, rb) do {                                                     \
        bf16x8 w0_, w1_;                                                        \
        _Pragma("unroll")                                                       \
        for (int j = 0; j < 8; ++j) { w0_[j] = (short)f2bf(rb[j]);              \
                                      w1_[j] = (short)f2bf(rb[8 + j]); }        \
        char* bs_ = (char*)(BsBase + (size_t)(ws * 2 + (b)) * BN * BK);         \
        *reinterpret_cast<bf16x8*>(bs_ + bcol * 128 + (((bkq * 2 + 0) ^ bsw) * 16)) = w0_; \
        *reinterpret_cast<bf16x8*>(bs_ + bcol * 128 + (((bkq * 2 + 1) ^ bsw) * 16)) = w1_; \
    } while (0)

#define LOADA2(ks, F) do {                                                      \
        _Pragma("unroll")                                                       \
        for (int mf = 0; mf < 4; ++mf)                                          \
            _Pragma("unroll")                                                   \
            for (int kk = 0; kk < 2; ++kk)                                      \
                F[mf * 2 + kk] = *reinterpret_cast<const bf16x8*>(              \
                    aBase + (size_t)mf * 16 * NN2 + (ks) * BK + kk * 32);       \
    } while (0)

#define MFMAPH2(b, F) do {                                                      \
        const char* bs_ = (const char*)(BsBase + (size_t)(ws * 2 + (b)) * BN * BK); \
        _Pragma("unroll")                                                       \
        for (int kk = 0; kk < 2; ++kk) {                                        \
            bf16x8 bf_[4];                                                      \
            _Pragma("unroll")                                                   \
            for (int nf = 0; nf < 4; ++nf) {                                    \
                const int col_ = nf * 16 + lrow;                                \
                bf_[nf] = *reinterpret_cast<const bf16x8*>(                     \
                    bs_ + col_ * 128 + (((kk * 4 + kg) ^ (col_ & 7)) * 16));    \
            }                                                                   \
            _Pragma("unroll")                                                   \
            for (int mf = 0; mf < 4; ++mf)                                      \
                _Pragma("unroll")                                               \
                for (int nf = 0; nf < 4; ++nf)                                  \
                    acc[mf][nf] = __builtin_amdgcn_mfma_f32_16x16x32_bf16(      \
                        F[mf * 2 + kk], bf_[nf], acc[mf][nf], 0, 0, 0);         \
        }                                                                       \
    } while (0)

    // prologue
    LOADB2(0, rb0);
    LOADB2(1, rb1);
    LOADA2(0, aF0);
    STOREB2(0, rb0);
    lgkm_bar();

    for (int j = 0; j < NS / 2; ++j) {
        const int ks = 2 * j;
        {
            const int ka = (ks + 1 < NS) ? ks + 1 : NS - 1;
            const int kb = (ks + 2 < NS) ? ks + 2 : NS - 1;
            LOADA2(ka, aF1);
            LOADB2(kb, rb0);
        }
        MFMAPH2(0, aF0);
        STOREB2(1, rb1);
        lgkm_bar();
        {
            const int ka = (ks + 2 < NS) ? ks + 2 : NS - 1;
            const int kb = (ks + 3 < NS) ? ks + 3 : NS - 1;
            LOADA2(ka, aF0);
            LOADB2(kb, rb1);
        }
        MFMAPH2(1, aF1);
        STOREB2(0, rb0);
        lgkm_bar();
    }
#undef LOADB2
#undef STOREB2
#undef LOADA2
#undef MFMAPH2

    // waveset reduce: ws1 partials -> LDS (smem reused), ws0 adds and
    // atomicAdds the kh-partial into the zeroed output.
    lgkm_bar();                                // all staging reads complete
    if (ws == 1) {
#pragma unroll
        for (int mf = 0; mf < 4; ++mf)
#pragma unroll
            for (int nf = 0; nf < 4; ++nf)
#pragma unroll
                for (int r = 0; r < 4; ++r) {
                    const int row = wr * 64 + mf * 16 + kg * 4 + r;
                    const int col = nf * 16 + lrow;
                    red[row * 64 + col] = acc[mf][nf][r];
                }
    }
    lgkm_bar();
    if (ws == 0) {
#pragma unroll
        for (int mf = 0; mf < 4; ++mf)
#pragma unroll
            for (int nf = 0; nf < 4; ++nf)
#pragma unroll
                for (int r = 0; r < 4; ++r) {
                    const int row = wr * 64 + mf * 16 + kg * 4 + r;
                    const int col = nf * 16 + lrow;
                    atomicAdd(&out[(size_t)(m0 + row) * HD + n0 + col],
                              acc[mf][nf][r] + red[row * 64 + col]);
                }
    }
}

// --------------------------------------------------------------- launch -----
extern "C" void kernel_launch(void* const* d_in, const int* in_sizes, int n_in,
                              void* d_out, int out_size, void* d_ws, size_t ws_size,
                              hipStream_t stream) {
    const float* x   = (const float*)d_in[0];
    const float* rw  = (const float*)d_in[1];
    const float* gup = (const float*)d_in[2];
    const float* dwn = (const float*)d_in[3];
    const float* sgw = (const float*)d_in[4];
    const float* suw = (const float*)d_in[5];
    const float* sdw = (const float*)d_in[6];

    float* out     = (float*)d_out;
    float* scoresT = out + (size_t)T_TOK * HD;

    char* ws   = (char*)d_ws;
    u16* xbf   = (u16*)ws;                                    // 4 MB
    u16* xsbf  = (u16*)(ws + (size_t)T_TOK * HD * 2);         // 4 MB
    u16* h2    = (u16*)(ws + (size_t)2 * T_TOK * HD * 2);     // 32 MB

    // zero the final-output region: G2 accumulates kh-partials atomically
    (void)hipMemsetAsync(out, 0, (size_t)T_TOK * HD * sizeof(float), stream);

    k_router<<<T_TOK, 256, 0, stream>>>(x, rw, scoresT, xbf, xsbf);
    k_gemm1<<<(T_TOK / 256) * (NN2 / 128), 512, 0, stream>>>(xbf, xsbf, sgw, suw, gup, h2);
    k_gemm2<<<256, 512, 0, stream>>>(h2, sdw, dwn, out);
}